// Round 1
// baseline (411.336 us; speedup 1.0000x reference)
//
#include <hip/hip_runtime.h>
#include <stdint.h>

#define Mdim 8192
#define Ndim 4096
#define Kdim 4096

typedef float f32x4 __attribute__((ext_vector_type(4)));
typedef __bf16 bf16x8 __attribute__((ext_vector_type(8)));
typedef unsigned short ushort_t;

#define FMAXC 3.3858093490333422e+38f  // FLT_MAX * (1 - 0.005)

__device__ __forceinline__ ushort_t f2bf(float f) {
    unsigned u = __float_as_uint(f);
    u += 0x7fffu + ((u >> 16) & 1u);   // round-to-nearest-even
    return (ushort_t)(u >> 16);
}

__device__ __forceinline__ void gload_lds16(const void* g, void* l) {
    __builtin_amdgcn_global_load_lds(
        (const __attribute__((address_space(1))) uint32_t*)g,
        (__attribute__((address_space(3))) uint32_t*)(uint32_t)(uintptr_t)l,
        16, 0, 0);
}

// ---------------------------------------------------------------------------
// Kernel 1: dequant one output row (4-bit bitplane LUT) + CSR outlier add,
// emit bf16 row. Block = 128 threads, one block per row o.
// LDS row is padded [128][33] so writes at (t,j) hit bank (t+j)%32 -> no
// conflicts (the naive [4096] layout is a 64-way conflict per instruction).
// ---------------------------------------------------------------------------
__global__ __launch_bounds__(128) void dequant_kernel(
        const int* __restrict__ qw, const float* __restrict__ lut,
        const int* __restrict__ rows, const int* __restrict__ cols,
        const float* __restrict__ vals, ushort_t* __restrict__ w16) {
    __shared__ float wrow[128 * 33];
    __shared__ float slut[16];
    const int o = blockIdx.x;
    const int t = threadIdx.x;

    if (t < 16) slut[t] = lut[o * 16 + t];
    __syncthreads();

    const int q0 = qw[0 * Ndim * 128 + o * 128 + t];
    const int q1 = qw[1 * Ndim * 128 + o * 128 + t];
    const int q2 = qw[2 * Ndim * 128 + o * 128 + t];
    const int q3 = qw[3 * Ndim * 128 + o * 128 + t];
    float* dst = &wrow[t * 33];
#pragma unroll
    for (int j = 0; j < 32; ++j) {
        int idx = (((q0 >> j) & 1) << 3) | (((q1 >> j) & 1) << 2) |
                  (((q2 >> j) & 1) << 1) | ((q3 >> j) & 1);
        dst[j] = slut[idx];
    }
    __syncthreads();

    // sparse outliers for this row (duplicates possible -> atomic on LDS)
    const int beg = rows[o], end = rows[o + 1];
    for (int k = beg + t; k < end; k += 128) {
        int c = cols[k];
        atomicAdd(&wrow[c + (c >> 5)], vals[k]);   // c/32*33 + c%32
    }
    __syncthreads();

    // convert + coalesced bf16 store (64B per thread)
    __align__(16) ushort_t tmp[32];
#pragma unroll
    for (int j = 0; j < 32; ++j) tmp[j] = f2bf(dst[j]);
    uint4* dstg = (uint4*)(w16 + (size_t)o * Kdim + t * 32);
    const uint4* srcg = (const uint4*)tmp;
#pragma unroll
    for (int j = 0; j < 4; ++j) dstg[j] = srcg[j];
}

// ---------------------------------------------------------------------------
// Kernel 2: x f32 -> bf16, 8 elements/thread, exact-size grid.
// ---------------------------------------------------------------------------
__global__ __launch_bounds__(256) void convx_kernel(
        const float* __restrict__ x, ushort_t* __restrict__ y) {
    size_t i = ((size_t)blockIdx.x * 256 + threadIdx.x) * 8;
    float4 a = *(const float4*)(x + i);
    float4 b = *(const float4*)(x + i + 4);
    __align__(16) ushort_t r[8] = {f2bf(a.x), f2bf(a.y), f2bf(a.z), f2bf(a.w),
                                   f2bf(b.x), f2bf(b.y), f2bf(b.z), f2bf(b.w)};
    *(uint4*)(y + i) = *(const uint4*)r;
}

// ---------------------------------------------------------------------------
// Kernel 3: bf16 GEMM  C[m][n] = sum_k A[m][k]*B[n][k] + bias[n], clipped.
// m97 structure: 128x128 tile, BK=32, 4 waves (2x2 of 64x64), 4x4 frags of
// mfma_f32_16x16x32_bf16, global_load_lds width-16 staging, XCD swizzle.
// ---------------------------------------------------------------------------
__global__ __launch_bounds__(256) void gemm_kernel(
        const ushort_t* __restrict__ A, const ushort_t* __restrict__ Bw,
        const float* __restrict__ bias, float* __restrict__ C) {
    __shared__ ushort_t As[128 * 32];
    __shared__ ushort_t Bs[128 * 32];

    // XCD-aware swizzle: nwg = 2048, 2048 % 8 == 0 -> simple form is bijective
    const int wg = blockIdx.x;
    const int swz = (wg & 7) * 256 + (wg >> 3);
    const int bm = swz & 63;          // M fastest: each XCD reuses a 4-row B panel (~4MB, L2-fit)
    const int bn = swz >> 6;
    const int m0 = bm * 128, n0 = bn * 128;

    const int t = threadIdx.x;
    const int lane = t & 63, wid = t >> 6;
    const int wr = wid >> 1, wc = wid & 1;

    f32x4 acc[4][4];
#pragma unroll
    for (int i = 0; i < 4; ++i)
#pragma unroll
        for (int j = 0; j < 4; ++j) acc[i][j] = (f32x4){0.f, 0.f, 0.f, 0.f};

    // staging addresses: thread t loads 16B = 8 bf16; issue j covers rows j*64..j*64+63
    const int srow = t >> 2;
    const int scol = (t & 3) * 8;
    const ushort_t* ga = A + (size_t)(m0 + srow) * Kdim + scol;
    const ushort_t* gb = Bw + (size_t)(n0 + srow) * Kdim + scol;
    char* la = (char*)As + t * 16;
    char* lb = (char*)Bs + t * 16;

    const int fr = lane & 15;       // fragment row/col within 16
    const int kg = lane >> 4;       // k-group of 8
    const ushort_t* pa = As + (wr * 64 + fr) * 32 + kg * 8;
    const ushort_t* pb = Bs + (wc * 64 + fr) * 32 + kg * 8;

    for (int kt = 0; kt < Kdim; kt += 32) {
        gload_lds16(ga + kt, la);
        gload_lds16(ga + kt + (size_t)64 * Kdim, la + 4096);
        gload_lds16(gb + kt, lb);
        gload_lds16(gb + kt + (size_t)64 * Kdim, lb + 4096);
        __syncthreads();

        bf16x8 af[4], bf[4];
#pragma unroll
        for (int m = 0; m < 4; ++m) af[m] = *(const bf16x8*)(pa + m * 16 * 32);
#pragma unroll
        for (int n = 0; n < 4; ++n) bf[n] = *(const bf16x8*)(pb + n * 16 * 32);
#pragma unroll
        for (int m = 0; m < 4; ++m)
#pragma unroll
            for (int n = 0; n < 4; ++n)
                acc[m][n] = __builtin_amdgcn_mfma_f32_16x16x32_bf16(
                    af[m], bf[n], acc[m][n], 0, 0, 0);
        __syncthreads();
    }

    // epilogue: C/D layout col = lane&15, row = (lane>>4)*4 + reg
    const int rg = lane >> 4;
#pragma unroll
    for (int n = 0; n < 4; ++n) {
        const int col = n0 + wc * 64 + n * 16 + fr;
        const float bv = bias[col];
#pragma unroll
        for (int m = 0; m < 4; ++m) {
            const int row = m0 + wr * 64 + m * 16 + rg * 4;
            float* outp = C + (size_t)row * Ndim + col;
#pragma unroll
            for (int j = 0; j < 4; ++j) {
                float v = acc[m][n][j] + bv;
                v = fminf(fmaxf(v, -FMAXC), FMAXC);
                outp[(size_t)j * Ndim] = v;
            }
        }
    }
}

extern "C" void kernel_launch(void* const* d_in, const int* in_sizes, int n_in,
                              void* d_out, int out_size, void* d_ws, size_t ws_size,
                              hipStream_t stream) {
    const float* x    = (const float*)d_in[0];
    const int*   qw   = (const int*)d_in[1];
    const float* lut  = (const float*)d_in[2];
    const int*   rows = (const int*)d_in[3];
    const int*   cols = (const int*)d_in[4];
    const float* vals = (const float*)d_in[5];
    const float* bias = (const float*)d_in[6];
    float* out = (float*)d_out;

    ushort_t* x16 = (ushort_t*)d_ws;                       // 8192*4096*2  = 64 MiB
    ushort_t* w16 = x16 + (size_t)Mdim * Kdim;             // 4096*4096*2  = 32 MiB

    hipLaunchKernelGGL(dequant_kernel, dim3(Ndim), dim3(128), 0, stream,
                       qw, lut, rows, cols, vals, w16);
    hipLaunchKernelGGL(convx_kernel, dim3((Mdim * Kdim) / (256 * 8)), dim3(256), 0, stream,
                       x, x16);
    hipLaunchKernelGGL(gemm_kernel, dim3((Mdim / 128) * (Ndim / 128)), dim3(256), 0, stream,
                       x16, w16, bias, out);
}

// Round 2
// 401.598 us; speedup vs baseline: 1.0242x; 1.0242x over previous
//
#include <hip/hip_runtime.h>
#include <stdint.h>

#define Mdim 8192
#define Ndim 4096
#define Kdim 4096

#define BM 256
#define BN 128
#define BK 64
#define NT (Kdim / BK)   // 64 K-tiles

typedef float f32x4 __attribute__((ext_vector_type(4)));
typedef __bf16 bf16x8 __attribute__((ext_vector_type(8)));
typedef unsigned short ushort_t;

#define FMAXC 3.3858093490333422e+38f  // FLT_MAX * (1 - 0.005)

__device__ __forceinline__ ushort_t f2bf(float f) {
    unsigned u = __float_as_uint(f);
    u += 0x7fffu + ((u >> 16) & 1u);   // round-to-nearest-even
    return (ushort_t)(u >> 16);
}

__device__ __forceinline__ void gload_lds16(const void* g, void* l) {
    __builtin_amdgcn_global_load_lds(
        (const __attribute__((address_space(1))) uint32_t*)g,
        (__attribute__((address_space(3))) uint32_t*)(uint32_t)(uintptr_t)l,
        16, 0, 0);
}

// ---------------------------------------------------------------------------
// Kernel 1: dequant one output row (4-bit bitplane LUT) + CSR outlier add,
// emit bf16 row. Unchanged from round 1 (passed, ~10 us).
// ---------------------------------------------------------------------------
__global__ __launch_bounds__(128) void dequant_kernel(
        const int* __restrict__ qw, const float* __restrict__ lut,
        const int* __restrict__ rows, const int* __restrict__ cols,
        const float* __restrict__ vals, ushort_t* __restrict__ w16) {
    __shared__ float wrow[128 * 33];
    __shared__ float slut[16];
    const int o = blockIdx.x;
    const int t = threadIdx.x;

    if (t < 16) slut[t] = lut[o * 16 + t];
    __syncthreads();

    const int q0 = qw[0 * Ndim * 128 + o * 128 + t];
    const int q1 = qw[1 * Ndim * 128 + o * 128 + t];
    const int q2 = qw[2 * Ndim * 128 + o * 128 + t];
    const int q3 = qw[3 * Ndim * 128 + o * 128 + t];
    float* dst = &wrow[t * 33];
#pragma unroll
    for (int j = 0; j < 32; ++j) {
        int idx = (((q0 >> j) & 1) << 3) | (((q1 >> j) & 1) << 2) |
                  (((q2 >> j) & 1) << 1) | ((q3 >> j) & 1);
        dst[j] = slut[idx];
    }
    __syncthreads();

    const int beg = rows[o], end = rows[o + 1];
    for (int k = beg + t; k < end; k += 128) {
        int c = cols[k];
        atomicAdd(&wrow[c + (c >> 5)], vals[k]);
    }
    __syncthreads();

    __align__(16) ushort_t tmp[32];
#pragma unroll
    for (int j = 0; j < 32; ++j) tmp[j] = f2bf(dst[j]);
    uint4* dstg = (uint4*)(w16 + (size_t)o * Kdim + t * 32);
    const uint4* srcg = (const uint4*)tmp;
#pragma unroll
    for (int j = 0; j < 4; ++j) dstg[j] = srcg[j];
}

// ---------------------------------------------------------------------------
// Kernel 2: x f32 -> bf16. Unchanged from round 1 (~30 us, HBM-bound).
// ---------------------------------------------------------------------------
__global__ __launch_bounds__(256) void convx_kernel(
        const float* __restrict__ x, ushort_t* __restrict__ y) {
    size_t i = ((size_t)blockIdx.x * 256 + threadIdx.x) * 8;
    float4 a = *(const float4*)(x + i);
    float4 b = *(const float4*)(x + i + 4);
    __align__(16) ushort_t r[8] = {f2bf(a.x), f2bf(a.y), f2bf(a.z), f2bf(a.w),
                                   f2bf(b.x), f2bf(b.y), f2bf(b.z), f2bf(b.w)};
    *(uint4*)(y + i) = *(const uint4*)r;
}

// ---------------------------------------------------------------------------
// Kernel 3: bf16 GEMM, 3-buffer-ring deep pipeline.
//   BM=256 BN=128 BK=64, 512 thr = 8 waves (4M x 2N), 64x64 per wave.
//   LDS ring: 3 x (A 32K + B 16K) = 144 KiB.  Prefetch distance 2 tiles ->
//   steady-state s_waitcnt vmcnt(6), never 0 in main loop (T3+T4).
//   T2: XOR swizzle byte^=((row&7)<<4); linear gload_lds dest + inverse-
//   swizzled global source + swizzled ds_read (both-sides rule).
//   T5: setprio(1) around each 16-MFMA cluster.
//   Raw asm s_barrier (memory clobber) -- no vmcnt(0) drain per step.
// Race-freedom: stage of tile t+2 into buf (t+2)%3 is issued during tile t;
// that buffer's previous tile (t-1) was last ds_read during tile t-1, with
// >=1 barrier and an lgkmcnt-complete point in between.
// ---------------------------------------------------------------------------
__global__ __launch_bounds__(512, 2) void gemm_kernel(
        const ushort_t* __restrict__ A, const ushort_t* __restrict__ Bw,
        const float* __restrict__ bias, float* __restrict__ C) {
    __shared__ __align__(16) char lds[147456];   // A: 3x32768 @0, B: 3x16384 @98304

    // XCD swizzle: nwg = 1024 (%8==0). Each XCD gets 4 consecutive bn panels
    // (4 MiB of B -> L2-resident) across all bm.
    const int wgid = blockIdx.x;
    const int swz = (wgid & 7) * 128 + (wgid >> 3);
    const int bm = swz & 31, bn = swz >> 5;
    const int m0 = bm * BM, n0 = bn * BN;

    const int tid = threadIdx.x;
    const int lane = tid & 63, wid = tid >> 6;
    const int wr = wid >> 1, wc = wid & 1;       // 4M x 2N wave grid
    const int fr = lane & 15, kg = lane >> 4;

    // ---- staging constants (inverse-swizzled global source, linear LDS dest)
    const int srow = tid >> 3;                               // 0..63
    const int scol = ((tid & 7) ^ (srow & 7)) * 8;           // elements
    const ushort_t* gA = A + (size_t)(m0 + srow) * Kdim + scol;
    const ushort_t* gB = Bw + (size_t)(n0 + srow) * Kdim + scol;
    char* lA = lds + tid * 16;
    char* lB = lds + 98304 + tid * 16;

    auto stageA = [&](int buf, int tt) {
#pragma unroll
        for (int j = 0; j < 4; ++j)
            gload_lds16(gA + (size_t)j * 64 * Kdim + tt * BK,
                        lA + buf * 32768 + j * 8192);
    };
    auto stageB = [&](int buf, int tt) {
#pragma unroll
        for (int j = 0; j < 2; ++j)
            gload_lds16(gB + (size_t)j * 64 * Kdim + tt * BK,
                        lB + buf * 16384 + j * 8192);
    };

    // ---- ds_read swizzled column offsets (bytes), per k-subtile
    const int swzr = (lane & 7) << 4;
    const int cb0 = ((0 << 6) | (kg << 4)) ^ swzr;
    const int cb1 = ((1 << 6) | (kg << 4)) ^ swzr;

    f32x4 acc[4][4];
#pragma unroll
    for (int i = 0; i < 4; ++i)
#pragma unroll
        for (int j = 0; j < 4; ++j) acc[i][j] = (f32x4){0.f, 0.f, 0.f, 0.f};

    // ---- prologue: stage tiles 0 and 1
    stageA(0, 0); stageB(0, 0);
    stageA(1, 1); stageB(1, 1);
    asm volatile("s_waitcnt vmcnt(6)" ::: "memory");   // tile 0 resident
    asm volatile("s_barrier" ::: "memory");

    int cur = 0;
#pragma unroll 1
    for (int t = 0; t < NT; ++t) {
        const char* Ab = lds + cur * 32768;
        const char* Bb = lds + 98304 + cur * 16384;
        const int nxt = (cur + 2 >= 3) ? cur - 1 : cur + 2;
        const bool pf = (t + 2 < NT);

        // ===== phase 1: k-subtile 0 =====
        bf16x8 a0[4], b0[4];
#pragma unroll
        for (int m = 0; m < 4; ++m)
            a0[m] = *(const bf16x8*)(Ab + (wr * 64 + m * 16 + fr) * 128 + cb0);
#pragma unroll
        for (int n = 0; n < 4; ++n)
            b0[n] = *(const bf16x8*)(Bb + (wc * 64 + n * 16 + fr) * 128 + cb0);
        if (pf) stageA(nxt, t + 2);
        asm volatile("s_barrier" ::: "memory");
        __builtin_amdgcn_s_setprio(1);
#pragma unroll
        for (int m = 0; m < 4; ++m)
#pragma unroll
            for (int n = 0; n < 4; ++n)
                acc[m][n] = __builtin_amdgcn_mfma_f32_16x16x32_bf16(
                    a0[m], b0[n], acc[m][n], 0, 0, 0);
        __builtin_amdgcn_s_setprio(0);
        asm volatile("s_barrier" ::: "memory");

        // ===== phase 2: k-subtile 1 =====
        bf16x8 a1[4], b1[4];
#pragma unroll
        for (int m = 0; m < 4; ++m)
            a1[m] = *(const bf16x8*)(Ab + (wr * 64 + m * 16 + fr) * 128 + cb1);
#pragma unroll
        for (int n = 0; n < 4; ++n)
            b1[n] = *(const bf16x8*)(Bb + (wc * 64 + n * 16 + fr) * 128 + cb1);
        if (pf) stageB(nxt, t + 2);
        asm volatile("s_barrier" ::: "memory");
        __builtin_amdgcn_s_setprio(1);
#pragma unroll
        for (int m = 0; m < 4; ++m)
#pragma unroll
            for (int n = 0; n < 4; ++n)
                acc[m][n] = __builtin_amdgcn_mfma_f32_16x16x32_bf16(
                    a1[m], b1[n], acc[m][n], 0, 0, 0);
        __builtin_amdgcn_s_setprio(0);

        if (t < NT - 2) {
            asm volatile("s_waitcnt vmcnt(6)" ::: "memory");   // tile t+1 resident
        } else if (t == NT - 2) {
            asm volatile("s_waitcnt vmcnt(0)" ::: "memory");   // final drain (once)
        }
        asm volatile("s_barrier" ::: "memory");

        cur = (cur == 2) ? 0 : cur + 1;
    }

    // ---- epilogue: C/D layout col = lane&15, row = (lane>>4)*4 + reg
    const int rg = lane >> 4;
#pragma unroll
    for (int n = 0; n < 4; ++n) {
        const int col = n0 + wc * 64 + n * 16 + fr;
        const float bv = bias[col];
#pragma unroll
        for (int m = 0; m < 4; ++m) {
            const int row = m0 + wr * 64 + m * 16 + rg * 4;
            float* outp = C + (size_t)row * Ndim + col;
#pragma unroll
            for (int j = 0; j < 4; ++j) {
                float v = acc[m][n][j] + bv;
                v = fminf(fmaxf(v, -FMAXC), FMAXC);
                outp[(size_t)j * Ndim] = v;
            }
        }
    }
}

extern "C" void kernel_launch(void* const* d_in, const int* in_sizes, int n_in,
                              void* d_out, int out_size, void* d_ws, size_t ws_size,
                              hipStream_t stream) {
    const float* x    = (const float*)d_in[0];
    const int*   qw   = (const int*)d_in[1];
    const float* lut  = (const float*)d_in[2];
    const int*   rows = (const int*)d_in[3];
    const int*   cols = (const int*)d_in[4];
    const float* vals = (const float*)d_in[5];
    const float* bias = (const float*)d_in[6];
    float* out = (float*)d_out;

    ushort_t* x16 = (ushort_t*)d_ws;                       // 64 MiB
    ushort_t* w16 = x16 + (size_t)Mdim * Kdim;             // 32 MiB

    hipLaunchKernelGGL(dequant_kernel, dim3(Ndim), dim3(128), 0, stream,
                       qw, lut, rows, cols, vals, w16);
    hipLaunchKernelGGL(convx_kernel, dim3((Mdim * Kdim) / (256 * 8)), dim3(256), 0, stream,
                       x, x16);
    hipLaunchKernelGGL(gemm_kernel, dim3((Mdim / BM) * (Ndim / BN)), dim3(512), 0, stream,
                       x16, w16, bias, out);
}

// Round 3
// 301.600 us; speedup vs baseline: 1.3638x; 1.3316x over previous
//
#include <hip/hip_runtime.h>
#include <stdint.h>

#define Mdim 8192
#define Ndim 4096
#define Kdim 4096

#define BM 256
#define BN 256
#define BK 32
#define NT (Kdim / BK)   // 128 K-tiles

typedef float f32x4 __attribute__((ext_vector_type(4)));
typedef __bf16 bf16x8 __attribute__((ext_vector_type(8)));
typedef unsigned short ushort_t;

#define FMAXC 3.3858093490333422e+38f  // FLT_MAX * (1 - 0.005)

__device__ __forceinline__ ushort_t f2bf(float f) {
    unsigned u = __float_as_uint(f);
    u += 0x7fffu + ((u >> 16) & 1u);   // round-to-nearest-even
    return (ushort_t)(u >> 16);
}

__device__ __forceinline__ void gload_lds16(const void* g, void* l) {
    __builtin_amdgcn_global_load_lds(
        (const __attribute__((address_space(1))) uint32_t*)g,
        (__attribute__((address_space(3))) uint32_t*)(uint32_t)(uintptr_t)l,
        16, 0, 0);
}

// ---------------------------------------------------------------------------
// Kernel 1: dequant + CSR outliers -> bf16 weight row. Unchanged (passed).
// ---------------------------------------------------------------------------
__global__ __launch_bounds__(128) void dequant_kernel(
        const int* __restrict__ qw, const float* __restrict__ lut,
        const int* __restrict__ rows, const int* __restrict__ cols,
        const float* __restrict__ vals, ushort_t* __restrict__ w16) {
    __shared__ float wrow[128 * 33];
    __shared__ float slut[16];
    const int o = blockIdx.x;
    const int t = threadIdx.x;

    if (t < 16) slut[t] = lut[o * 16 + t];
    __syncthreads();

    const int q0 = qw[0 * Ndim * 128 + o * 128 + t];
    const int q1 = qw[1 * Ndim * 128 + o * 128 + t];
    const int q2 = qw[2 * Ndim * 128 + o * 128 + t];
    const int q3 = qw[3 * Ndim * 128 + o * 128 + t];
    float* dst = &wrow[t * 33];
#pragma unroll
    for (int j = 0; j < 32; ++j) {
        int idx = (((q0 >> j) & 1) << 3) | (((q1 >> j) & 1) << 2) |
                  (((q2 >> j) & 1) << 1) | ((q3 >> j) & 1);
        dst[j] = slut[idx];
    }
    __syncthreads();

    const int beg = rows[o], end = rows[o + 1];
    for (int k = beg + t; k < end; k += 128) {
        int c = cols[k];
        atomicAdd(&wrow[c + (c >> 5)], vals[k]);
    }
    __syncthreads();

    __align__(16) ushort_t tmp[32];
#pragma unroll
    for (int j = 0; j < 32; ++j) tmp[j] = f2bf(dst[j]);
    uint4* dstg = (uint4*)(w16 + (size_t)o * Kdim + t * 32);
    const uint4* srcg = (const uint4*)tmp;
#pragma unroll
    for (int j = 0; j < 4; ++j) dstg[j] = srcg[j];
}

// ---------------------------------------------------------------------------
// Kernel 2: x f32 -> bf16. Unchanged (HBM-bound, ~30 us).
// ---------------------------------------------------------------------------
__global__ __launch_bounds__(256) void convx_kernel(
        const float* __restrict__ x, ushort_t* __restrict__ y) {
    size_t i = ((size_t)blockIdx.x * 256 + threadIdx.x) * 8;
    float4 a = *(const float4*)(x + i);
    float4 b = *(const float4*)(x + i + 4);
    __align__(16) ushort_t r[8] = {f2bf(a.x), f2bf(a.y), f2bf(a.z), f2bf(a.w),
                                   f2bf(b.x), f2bf(b.y), f2bf(b.z), f2bf(b.w)};
    *(uint4*)(y + i) = *(const uint4*)r;
}

// ---------------------------------------------------------------------------
// Kernel 3: bf16 GEMM, 256x256 tile, BK=32, 4-buffer LDS ring, counted vmcnt.
//   8 waves (2M x 4N), wave tile 128x64, acc[8][4] (128 VGPR).
//   LDS 128 KiB: A ring 4x16KB @0, B ring 4x16KB @65536.
//   Paired-row swizzled layout (zero-conflict for 64-B k-rows):
//     byte(row,ks,b) = (row>>1)*128 + ((((row&1)<<2)|ks) ^ ((row>>1)&7))*16 + b
//   realized as linear gload_lds dest + inverse-swizzled global source.
//   Ring distance 2: stage K-tile t+2 during tile t; vmcnt(4) once per tile.
//   Race-free: buf (t+2)&3 last read in tile t-2 (lgkm-drained, 2+ barriers
//   before the stage issues); write-write drained 2 tiles prior.
// ---------------------------------------------------------------------------
__global__ __launch_bounds__(512, 2) void gemm_kernel(
        const ushort_t* __restrict__ A, const ushort_t* __restrict__ Bw,
        const float* __restrict__ bias, float* __restrict__ C) {
    __shared__ __align__(16) char lds[131072];

    // XCD swizzle, bn-fastest: 32 concurrent blocks per XCD share one A panel
    // (2 bm values = 4 MiB -> L2-resident), stream B via L3. nwg=512 (%8==0).
    const int wgid = blockIdx.x;
    const int swz = (wgid & 7) * 64 + (wgid >> 3);
    const int bn = swz & 15, bm = swz >> 4;
    const int m0 = bm * BM, n0 = bn * BN;

    const int tid = threadIdx.x;
    const int lane = tid & 63, wid = tid >> 6;
    const int wr = wid >> 2, wc = wid & 3;       // 2M x 4N wave grid
    const int fr = lane & 15, kg = lane >> 4;

    // ---- staging geometry: thread tid, load j in {0,1}:
    //   LDS offset o = tid*16 + j*8192 ; line = tid>>3 + j*64 ; sl = tid&7
    //   slot = sl ^ (line&7) ; row = 2*line + (slot>>2) ; kbyte = (slot&3)*16
    const int sline = tid >> 3;
    const int slot = (tid & 7) ^ (sline & 7);
    const int srow0 = (sline << 1) + (slot >> 2);          // + j*128
    const int skel = (slot & 3) * 8;                       // k elements
    const ushort_t* gA = A + (size_t)(m0 + srow0) * Kdim + skel;
    const ushort_t* gB = Bw + (size_t)(n0 + srow0) * Kdim + skel;

    auto stageA = [&](int bufd, int t2) {
        const ushort_t* s = gA + (size_t)t2 * BK;
        char* d = lds + bufd * 16384 + tid * 16;
        gload_lds16(s, d);
        gload_lds16(s + (size_t)128 * Kdim, d + 8192);
    };
    auto stageB = [&](int bufd, int t2) {
        const ushort_t* s = gB + (size_t)t2 * BK;
        char* d = lds + 65536 + bufd * 16384 + tid * 16;
        gload_lds16(s, d);
        gload_lds16(s + (size_t)128 * Kdim, d + 8192);
    };

    // ---- ds_read lane offset (row = 16-aligned-base + fr, kslot = kg):
    //   (fr>>1)*128 + ((((fr&1)<<2)|kg) ^ (fr>>1))*16
    const int offL = (fr >> 1) * 128 + (((((fr & 1) << 2) | kg) ^ (fr >> 1)) << 4);

    f32x4 acc[8][4];
#pragma unroll
    for (int i = 0; i < 8; ++i)
#pragma unroll
        for (int j = 0; j < 4; ++j) acc[i][j] = (f32x4){0.f, 0.f, 0.f, 0.f};

    // ---- prologue: stage tiles 0,1 -> bufs 0,1; wait tile 0 (4 outstanding)
    stageA(0, 0); stageB(0, 0);
    stageA(1, 1); stageB(1, 1);
    asm volatile("s_waitcnt vmcnt(4)" ::: "memory");
    asm volatile("s_barrier" ::: "memory");

#pragma unroll 1
    for (int t = 0; t < NT; ++t) {
        const int bufi = t & 3;
        const int buf2 = (t + 2) & 3;
        const bool pf = (t + 2 < NT);
        const char* Ab = lds + bufi * 16384;
        const char* Bb = lds + 65536 + bufi * 16384;

        // ===== phase 0: A[m0-3] + B[all n], MFMA quadrant m0-3 x n0-3 =====
        bf16x8 Af0[4], Bf[4];
#pragma unroll
        for (int m = 0; m < 4; ++m)
            Af0[m] = *(const bf16x8*)(Ab + wr * 8192 + m * 1024 + offL);
#pragma unroll
        for (int n = 0; n < 4; ++n)
            Bf[n] = *(const bf16x8*)(Bb + wc * 4096 + n * 1024 + offL);
        if (pf) stageA(buf2, t + 2);
        asm volatile("s_barrier" ::: "memory");
        asm volatile("s_waitcnt lgkmcnt(0)" ::: "memory");
        __builtin_amdgcn_s_setprio(1);
#pragma unroll
        for (int m = 0; m < 4; ++m)
#pragma unroll
            for (int n = 0; n < 4; ++n)
                acc[m][n] = __builtin_amdgcn_mfma_f32_16x16x32_bf16(
                    Af0[m], Bf[n], acc[m][n], 0, 0, 0);
        __builtin_amdgcn_s_setprio(0);
        asm volatile("s_barrier" ::: "memory");

        // ===== phase 1: A[m4-7], MFMA quadrant m4-7 x n0-3 =====
        bf16x8 Af1[4];
#pragma unroll
        for (int m = 0; m < 4; ++m)
            Af1[m] = *(const bf16x8*)(Ab + wr * 8192 + (m + 4) * 1024 + offL);
        if (pf) stageB(buf2, t + 2);
        asm volatile("s_barrier" ::: "memory");
        asm volatile("s_waitcnt lgkmcnt(0)" ::: "memory");
        __builtin_amdgcn_s_setprio(1);
#pragma unroll
        for (int m = 0; m < 4; ++m)
#pragma unroll
            for (int n = 0; n < 4; ++n)
                acc[m + 4][n] = __builtin_amdgcn_mfma_f32_16x16x32_bf16(
                    Af1[m], Bf[n], acc[m + 4][n], 0, 0, 0);
        __builtin_amdgcn_s_setprio(0);
        if (t < NT - 2) {
            asm volatile("s_waitcnt vmcnt(4)" ::: "memory");   // tile t+1 resident
        } else if (t == NT - 2) {
            asm volatile("s_waitcnt vmcnt(0)" ::: "memory");   // final drain (once)
        }
        asm volatile("s_barrier" ::: "memory");
    }

    // ---- epilogue: C/D layout col = lane&15, row = (lane>>4)*4 + reg
    const int rg = lane >> 4;
#pragma unroll
    for (int nf = 0; nf < 4; ++nf) {
        const int col = n0 + wc * 64 + nf * 16 + fr;
        const float bv = bias[col];
#pragma unroll
        for (int mf = 0; mf < 8; ++mf) {
            const int row = m0 + wr * 128 + mf * 16 + rg * 4;
            float* outp = C + (size_t)row * Ndim + col;
#pragma unroll
            for (int j = 0; j < 4; ++j) {
                float v = acc[mf][nf][j] + bv;
                v = fminf(fmaxf(v, -FMAXC), FMAXC);
                outp[(size_t)j * Ndim] = v;
            }
        }
    }
}

extern "C" void kernel_launch(void* const* d_in, const int* in_sizes, int n_in,
                              void* d_out, int out_size, void* d_ws, size_t ws_size,
                              hipStream_t stream) {
    const float* x    = (const float*)d_in[0];
    const int*   qw   = (const int*)d_in[1];
    const float* lut  = (const float*)d_in[2];
    const int*   rows = (const int*)d_in[3];
    const int*   cols = (const int*)d_in[4];
    const float* vals = (const float*)d_in[5];
    const float* bias = (const float*)d_in[6];
    float* out = (float*)d_out;

    ushort_t* x16 = (ushort_t*)d_ws;                       // 64 MiB
    ushort_t* w16 = x16 + (size_t)Mdim * Kdim;             // 32 MiB

    hipLaunchKernelGGL(dequant_kernel, dim3(Ndim), dim3(128), 0, stream,
                       qw, lut, rows, cols, vals, w16);
    hipLaunchKernelGGL(convx_kernel, dim3((Mdim * Kdim) / (256 * 8)), dim3(256), 0, stream,
                       x, x16);
    hipLaunchKernelGGL(gemm_kernel, dim3((Mdim / BM) * (Ndim / BN)), dim3(512), 0, stream,
                       x16, w16, bias, out);
}

// Round 4
// 292.421 us; speedup vs baseline: 1.4067x; 1.0314x over previous
//
#include <hip/hip_runtime.h>
#include <stdint.h>

#define Mdim 8192
#define Ndim 4096
#define Kdim 4096

#define BM 256
#define BN 256
#define BK 32
#define NT (Kdim / BK)   // 128 K-tiles

typedef float f32x4 __attribute__((ext_vector_type(4)));
typedef __bf16 bf16x8 __attribute__((ext_vector_type(8)));
typedef unsigned short ushort_t;

#define FMAXC 3.3858093490333422e+38f  // FLT_MAX * (1 - 0.005)

__device__ __forceinline__ ushort_t f2bf(float f) {
    unsigned u = __float_as_uint(f);
    u += 0x7fffu + ((u >> 16) & 1u);   // round-to-nearest-even
    return (ushort_t)(u >> 16);
}

__device__ __forceinline__ void gload_lds16(const void* g, void* l) {
    __builtin_amdgcn_global_load_lds(
        (const __attribute__((address_space(1))) uint32_t*)g,
        (__attribute__((address_space(3))) uint32_t*)(uint32_t)(uintptr_t)l,
        16, 0, 0);
}

// ---------------------------------------------------------------------------
// Kernel 1: dequant + CSR outliers -> bf16 weight row. Unchanged (passed).
// ---------------------------------------------------------------------------
__global__ __launch_bounds__(128) void dequant_kernel(
        const int* __restrict__ qw, const float* __restrict__ lut,
        const int* __restrict__ rows, const int* __restrict__ cols,
        const float* __restrict__ vals, ushort_t* __restrict__ w16) {
    __shared__ float wrow[128 * 33];
    __shared__ float slut[16];
    const int o = blockIdx.x;
    const int t = threadIdx.x;

    if (t < 16) slut[t] = lut[o * 16 + t];
    __syncthreads();

    const int q0 = qw[0 * Ndim * 128 + o * 128 + t];
    const int q1 = qw[1 * Ndim * 128 + o * 128 + t];
    const int q2 = qw[2 * Ndim * 128 + o * 128 + t];
    const int q3 = qw[3 * Ndim * 128 + o * 128 + t];
    float* dst = &wrow[t * 33];
#pragma unroll
    for (int j = 0; j < 32; ++j) {
        int idx = (((q0 >> j) & 1) << 3) | (((q1 >> j) & 1) << 2) |
                  (((q2 >> j) & 1) << 1) | ((q3 >> j) & 1);
        dst[j] = slut[idx];
    }
    __syncthreads();

    const int beg = rows[o], end = rows[o + 1];
    for (int k = beg + t; k < end; k += 128) {
        int c = cols[k];
        atomicAdd(&wrow[c + (c >> 5)], vals[k]);
    }
    __syncthreads();

    __align__(16) ushort_t tmp[32];
#pragma unroll
    for (int j = 0; j < 32; ++j) tmp[j] = f2bf(dst[j]);
    uint4* dstg = (uint4*)(w16 + (size_t)o * Kdim + t * 32);
    const uint4* srcg = (const uint4*)tmp;
#pragma unroll
    for (int j = 0; j < 4; ++j) dstg[j] = srcg[j];
}

// ---------------------------------------------------------------------------
// Kernel 2: x f32 -> bf16. Unchanged (HBM-bound, ~30 us).
// ---------------------------------------------------------------------------
__global__ __launch_bounds__(256) void convx_kernel(
        const float* __restrict__ x, ushort_t* __restrict__ y) {
    size_t i = ((size_t)blockIdx.x * 256 + threadIdx.x) * 8;
    float4 a = *(const float4*)(x + i);
    float4 b = *(const float4*)(x + i + 4);
    __align__(16) ushort_t r[8] = {f2bf(a.x), f2bf(a.y), f2bf(a.z), f2bf(a.w),
                                   f2bf(b.x), f2bf(b.y), f2bf(b.z), f2bf(b.w)};
    *(uint4*)(y + i) = *(const uint4*)r;
}

// ---------------------------------------------------------------------------
// Kernel 3: bf16 GEMM, 256x256 tile, BK=32, 4-buffer LDS ring, counted vmcnt,
// ONE barrier per K-tile (compiler-scheduled tile body).
//   8 waves (2M x 4N), wave tile 128x64, acc[8][4].
//   LDS 128 KiB: A ring 4x16KB @0, B ring 4x16KB @65536.
//   Zero-conflict paired-row swizzle (measured 0 conflicts), realized as
//   linear gload_lds dest + inverse-swizzled global source + swizzled read.
// Ring correctness with ONE {vmcnt(4); s_barrier} per tile:
//   RAW: per-wave vmcnt(4) at end of tile t leaves only tile-(t+2) loads
//        outstanding -> all waves' (t+1) loads landed before the barrier
//        releases anyone into tile t+1.
//   WAR: stage(t+2) writes buf (t+2)&3 == (t-2)&3; every wave's reads of
//        that buf retired (lgkm consumed by its MFMAs) before it passed the
//        end-of-(t-2) barrier, two barriers before any stage(t+2) issues.
//   Drift: single barrier per tile bounds wave skew to < 1 tile.
// ---------------------------------------------------------------------------
__global__ __launch_bounds__(512, 2) void gemm_kernel(
        const ushort_t* __restrict__ A, const ushort_t* __restrict__ Bw,
        const float* __restrict__ bias, float* __restrict__ C) {
    __shared__ __align__(16) char lds[131072];

    // XCD swizzle, bn-fastest: 32 concurrent blocks per XCD share one A panel
    // (L2-resident), stream B via L3. nwg=512 (%8==0).
    const int wgid = blockIdx.x;
    const int swz = (wgid & 7) * 64 + (wgid >> 3);
    const int bn = swz & 15, bm = swz >> 4;
    const int m0 = bm * BM, n0 = bn * BN;

    const int tid = threadIdx.x;
    const int lane = tid & 63, wid = tid >> 6;
    const int wr = wid >> 2, wc = wid & 3;       // 2M x 4N wave grid
    const int fr = lane & 15, kg = lane >> 4;

    // ---- staging geometry (inverse-swizzled global source, linear LDS dest)
    const int sline = tid >> 3;
    const int slot = (tid & 7) ^ (sline & 7);
    const int srow0 = (sline << 1) + (slot >> 2);          // + j*128
    const int skel = (slot & 3) * 8;                       // k elements
    const ushort_t* gA = A + (size_t)(m0 + srow0) * Kdim + skel;
    const ushort_t* gB = Bw + (size_t)(n0 + srow0) * Kdim + skel;

    // ---- ds_read lane offset (row = base + fr, kslot = kg)
    const int offL = (fr >> 1) * 128 + (((((fr & 1) << 2) | kg) ^ (fr >> 1)) << 4);

    f32x4 acc[8][4];
#pragma unroll
    for (int i = 0; i < 8; ++i)
#pragma unroll
        for (int j = 0; j < 4; ++j) acc[i][j] = (f32x4){0.f, 0.f, 0.f, 0.f};

    // running stage pointers: at loop iteration t they point at K-tile t+2
    const ushort_t* pA = gA;
    const ushort_t* pB = gB;

    auto stageA = [&](int bufd) {
        char* d = lds + bufd * 16384 + tid * 16;
        gload_lds16(pA, d);
        gload_lds16(pA + (size_t)128 * Kdim, d + 8192);
    };
    auto stageB = [&](int bufd) {
        char* d = lds + 65536 + bufd * 16384 + tid * 16;
        gload_lds16(pB, d);
        gload_lds16(pB + (size_t)128 * Kdim, d + 8192);
    };

    // ---- prologue: stage tiles 0,1 -> bufs 0,1; wait tile 0 (4 outstanding)
    stageA(0); stageB(0); pA += BK; pB += BK;
    stageA(1); stageB(1); pA += BK; pB += BK;
    asm volatile("s_waitcnt vmcnt(4)" ::: "memory");
    asm volatile("s_barrier" ::: "memory");

#pragma unroll 1
    for (int t = 0; t < NT; ++t) {
        const int bufi = t & 3;
        const int buf2 = (t + 2) & 3;
        const char* Ab = lds + bufi * 16384;
        const char* Bb = lds + 65536 + bufi * 16384;

        // stage K-tile t+2 (issue early; lands any time before end-of-(t+1))
        if (t + 2 < NT) {
            stageA(buf2);
            stageB(buf2);
        }
        pA += BK; pB += BK;

        // all 12 fragment reads for this tile (compiler interleaves lgkmcnt)
        bf16x8 Af[8], Bf[4];
#pragma unroll
        for (int n = 0; n < 4; ++n) {
            Af[n] = *(const bf16x8*)(Ab + wr * 8192 + n * 1024 + offL);
            Bf[n] = *(const bf16x8*)(Bb + wc * 4096 + n * 1024 + offL);
        }
#pragma unroll
        for (int m = 4; m < 8; ++m)
            Af[m] = *(const bf16x8*)(Ab + wr * 8192 + m * 1024 + offL);

        __builtin_amdgcn_s_setprio(1);
#pragma unroll
        for (int m = 0; m < 4; ++m)
#pragma unroll
            for (int n = 0; n < 4; ++n)
                acc[m][n] = __builtin_amdgcn_mfma_f32_16x16x32_bf16(
                    Af[m], Bf[n], acc[m][n], 0, 0, 0);
#pragma unroll
        for (int m = 4; m < 8; ++m)
#pragma unroll
            for (int n = 0; n < 4; ++n)
                acc[m][n] = __builtin_amdgcn_mfma_f32_16x16x32_bf16(
                    Af[m], Bf[n], acc[m][n], 0, 0, 0);
        __builtin_amdgcn_s_setprio(0);

        if (t < NT - 2) {
            asm volatile("s_waitcnt vmcnt(4)" ::: "memory");   // tile t+1 resident
        } else if (t == NT - 2) {
            asm volatile("s_waitcnt vmcnt(0)" ::: "memory");   // final drain (once)
        }
        asm volatile("s_barrier" ::: "memory");
    }

    // ---- epilogue: C/D layout col = lane&15, row = (lane>>4)*4 + reg
    const int rg = lane >> 4;
#pragma unroll
    for (int nf = 0; nf < 4; ++nf) {
        const int col = n0 + wc * 64 + nf * 16 + fr;
        const float bv = bias[col];
#pragma unroll
        for (int mf = 0; mf < 8; ++mf) {
            const int row = m0 + wr * 128 + mf * 16 + rg * 4;
            float* outp = C + (size_t)row * Ndim + col;
#pragma unroll
            for (int j = 0; j < 4; ++j) {
                float v = acc[mf][nf][j] + bv;
                v = fminf(fmaxf(v, -FMAXC), FMAXC);
                outp[(size_t)j * Ndim] = v;
            }
        }
    }
}

extern "C" void kernel_launch(void* const* d_in, const int* in_sizes, int n_in,
                              void* d_out, int out_size, void* d_ws, size_t ws_size,
                              hipStream_t stream) {
    const float* x    = (const float*)d_in[0];
    const int*   qw   = (const int*)d_in[1];
    const float* lut  = (const float*)d_in[2];
    const int*   rows = (const int*)d_in[3];
    const int*   cols = (const int*)d_in[4];
    const float* vals = (const float*)d_in[5];
    const float* bias = (const float*)d_in[6];
    float* out = (float*)d_out;

    ushort_t* x16 = (ushort_t*)d_ws;                       // 64 MiB
    ushort_t* w16 = x16 + (size_t)Mdim * Kdim;             // 32 MiB

    hipLaunchKernelGGL(dequant_kernel, dim3(Ndim), dim3(128), 0, stream,
                       qw, lut, rows, cols, vals, w16);
    hipLaunchKernelGGL(convx_kernel, dim3((Mdim * Kdim) / (256 * 8)), dim3(256), 0, stream,
                       x, x16);
    hipLaunchKernelGGL(gemm_kernel, dim3((Mdim / BM) * (Ndim / BN)), dim3(512), 0, stream,
                       x16, w16, bias, out);
}

// Round 5
// 290.308 us; speedup vs baseline: 1.4169x; 1.0073x over previous
//
#include <hip/hip_runtime.h>
#include <stdint.h>

#define Mdim 8192
#define Ndim 4096
#define Kdim 4096

#define BM 256
#define BN 256
#define BK 32
#define NT (Kdim / BK)   // 128 K-tiles

typedef float f32x4 __attribute__((ext_vector_type(4)));
typedef __bf16 bf16x8 __attribute__((ext_vector_type(8)));
typedef unsigned short ushort_t;

#define FMAXC 3.3858093490333422e+38f  // FLT_MAX * (1 - 0.005)

__device__ __forceinline__ ushort_t f2bf(float f) {
    unsigned u = __float_as_uint(f);
    u += 0x7fffu + ((u >> 16) & 1u);   // round-to-nearest-even
    return (ushort_t)(u >> 16);
}

__device__ __forceinline__ void gload_lds16(const void* g, void* l) {
    __builtin_amdgcn_global_load_lds(
        (const __attribute__((address_space(1))) uint32_t*)g,
        (__attribute__((address_space(3))) uint32_t*)(uint32_t)(uintptr_t)l,
        16, 0, 0);
}

// ---------------------------------------------------------------------------
// Kernel 1: dequant + CSR outliers -> bf16 weight row. Unchanged (passed).
// ---------------------------------------------------------------------------
__global__ __launch_bounds__(128) void dequant_kernel(
        const int* __restrict__ qw, const float* __restrict__ lut,
        const int* __restrict__ rows, const int* __restrict__ cols,
        const float* __restrict__ vals, ushort_t* __restrict__ w16) {
    __shared__ float wrow[128 * 33];
    __shared__ float slut[16];
    const int o = blockIdx.x;
    const int t = threadIdx.x;

    if (t < 16) slut[t] = lut[o * 16 + t];
    __syncthreads();

    const int q0 = qw[0 * Ndim * 128 + o * 128 + t];
    const int q1 = qw[1 * Ndim * 128 + o * 128 + t];
    const int q2 = qw[2 * Ndim * 128 + o * 128 + t];
    const int q3 = qw[3 * Ndim * 128 + o * 128 + t];
    float* dst = &wrow[t * 33];
#pragma unroll
    for (int j = 0; j < 32; ++j) {
        int idx = (((q0 >> j) & 1) << 3) | (((q1 >> j) & 1) << 2) |
                  (((q2 >> j) & 1) << 1) | ((q3 >> j) & 1);
        dst[j] = slut[idx];
    }
    __syncthreads();

    const int beg = rows[o], end = rows[o + 1];
    for (int k = beg + t; k < end; k += 128) {
        int c = cols[k];
        atomicAdd(&wrow[c + (c >> 5)], vals[k]);
    }
    __syncthreads();

    __align__(16) ushort_t tmp[32];
#pragma unroll
    for (int j = 0; j < 32; ++j) tmp[j] = f2bf(dst[j]);
    uint4* dstg = (uint4*)(w16 + (size_t)o * Kdim + t * 32);
    const uint4* srcg = (const uint4*)tmp;
#pragma unroll
    for (int j = 0; j < 4; ++j) dstg[j] = srcg[j];
}

// ---------------------------------------------------------------------------
// Kernel 2: x f32 -> bf16. Unchanged (HBM-bound, ~30 us).
// ---------------------------------------------------------------------------
__global__ __launch_bounds__(256) void convx_kernel(
        const float* __restrict__ x, ushort_t* __restrict__ y) {
    size_t i = ((size_t)blockIdx.x * 256 + threadIdx.x) * 8;
    float4 a = *(const float4*)(x + i);
    float4 b = *(const float4*)(x + i + 4);
    __align__(16) ushort_t r[8] = {f2bf(a.x), f2bf(a.y), f2bf(a.z), f2bf(a.w),
                                   f2bf(b.x), f2bf(b.y), f2bf(b.z), f2bf(b.w)};
    *(uint4*)(y + i) = *(const uint4*)r;
}

// ---------------------------------------------------------------------------
// Kernel 3: bf16 GEMM, 256x256 tile, BK=32, 4-buffer LDS ring,
// CROSS-TILE REGISTER FRAGMENT PREFETCH (tile t's MFMAs overlap tile t+1's
// ds_reads -> LDS port and matrix pipe run concurrently).
//   8 waves (2M x 4N), wave tile 128x64, acc[8][4]; frag sets a/b (named,
//   statically indexed -> registers; loop unrolled x2).
//   LDS 128 KiB: A ring 4x16KB @0, B ring 4x16KB @65536.
//   Zero-conflict paired-row swizzle (measured 0 conflicts): linear
//   gload_lds dest + inverse-swizzled global source + swizzled ds_read.
// Pipeline (stage distance 3):
//   iter t: read frags(t+1) ; stage tile t+3 ; MFMA(t) ; vmcnt(4) ; barrier
//   vmcnt(4) at end of t leaves only tile-(t+3) loads outstanding ->
//   tile t+2 is LDS-resident before iter t+1 reads its fragments.
// WAR: stage(t+3) writes buf (t+3)&3 = (t-1)&3, whose frags were read during
//   iter t-2; those ds_reads were register-retired (consumed by MFMAs of
//   tile t-1) before the end-of-(t-1) barrier, which precedes this stage.
// ---------------------------------------------------------------------------
__global__ __launch_bounds__(512, 2) void gemm_kernel(
        const ushort_t* __restrict__ A, const ushort_t* __restrict__ Bw,
        const float* __restrict__ bias, float* __restrict__ C) {
    __shared__ __align__(16) char lds[131072];

    // XCD swizzle, bn-fastest: 32 concurrent blocks per XCD share one A panel
    // (L2-resident), stream B via L3. nwg=512 (%8==0).
    const int wgid = blockIdx.x;
    const int swz = (wgid & 7) * 64 + (wgid >> 3);
    const int bn = swz & 15, bm = swz >> 4;
    const int m0 = bm * BM, n0 = bn * BN;

    const int tid = threadIdx.x;
    const int lane = tid & 63, wid = tid >> 6;
    const int wr = wid >> 2, wc = wid & 3;       // 2M x 4N wave grid
    const int fr = lane & 15, kg = lane >> 4;

    // ---- staging geometry (inverse-swizzled global source, linear LDS dest)
    const int sline = tid >> 3;
    const int slot = (tid & 7) ^ (sline & 7);
    const int srow0 = (sline << 1) + (slot >> 2);          // + j*128
    const int skel = (slot & 3) * 8;                       // k elements
    const ushort_t* gA = A + (size_t)(m0 + srow0) * Kdim + skel;
    const ushort_t* gB = Bw + (size_t)(n0 + srow0) * Kdim + skel;

    // ---- ds_read lane offset (row = base + fr, kslot = kg)
    const int offL = (fr >> 1) * 128 + (((((fr & 1) << 2) | kg) ^ (fr >> 1)) << 4);

    f32x4 acc[8][4];
#pragma unroll
    for (int i = 0; i < 8; ++i)
#pragma unroll
        for (int j = 0; j < 4; ++j) acc[i][j] = (f32x4){0.f, 0.f, 0.f, 0.f};

    // running stage pointers: advance BK per tile staged
    const ushort_t* pA = gA;
    const ushort_t* pB = gB;

    auto stageA = [&](int bufd) {
        char* d = lds + bufd * 16384 + tid * 16;
        gload_lds16(pA, d);
        gload_lds16(pA + (size_t)128 * Kdim, d + 8192);
    };
    auto stageB = [&](int bufd) {
        char* d = lds + 65536 + bufd * 16384 + tid * 16;
        gload_lds16(pB, d);
        gload_lds16(pB + (size_t)128 * Kdim, d + 8192);
    };
    auto readFrags = [&](bf16x8 (&FA)[8], bf16x8 (&FB)[4], int bufidx) {
        const char* Ab = lds + bufidx * 16384;
        const char* Bb = lds + 65536 + bufidx * 16384;
#pragma unroll
        for (int n = 0; n < 4; ++n) {
            FA[n] = *(const bf16x8*)(Ab + wr * 8192 + n * 1024 + offL);
            FB[n] = *(const bf16x8*)(Bb + wc * 4096 + n * 1024 + offL);
        }
#pragma unroll
        for (int m = 4; m < 8; ++m)
            FA[m] = *(const bf16x8*)(Ab + wr * 8192 + m * 1024 + offL);
    };
    auto mfmaTile = [&](bf16x8 (&FA)[8], bf16x8 (&FB)[4]) {
        __builtin_amdgcn_s_setprio(1);
#pragma unroll
        for (int m = 0; m < 8; ++m)
#pragma unroll
            for (int n = 0; n < 4; ++n)
                acc[m][n] = __builtin_amdgcn_mfma_f32_16x16x32_bf16(
                    FA[m], FB[n], acc[m][n], 0, 0, 0);
        __builtin_amdgcn_s_setprio(0);
    };

    // ---- prologue: stage tiles 0,1,2 -> bufs 0,1,2
    stageA(0); stageB(0); pA += BK; pB += BK;
    stageA(1); stageB(1); pA += BK; pB += BK;
    stageA(2); stageB(2); pA += BK; pB += BK;
    asm volatile("s_waitcnt vmcnt(4)" ::: "memory");   // tiles 0,1 resident
    asm volatile("s_barrier" ::: "memory");

    bf16x8 FAa[8], FAb[8];
    bf16x8 FBa[4], FBb[4];
    readFrags(FAa, FBa, 0);                            // tile 0 -> set a

#pragma unroll 1
    for (int t = 0; t < NT; t += 2) {
        // ===== half 1: compute tile t (set a); read tile t+1 -> set b =====
        readFrags(FAb, FBb, (t + 1) & 3);              // t+1 <= NT-1 always
        if (t + 3 < NT) { stageA((t + 3) & 3); stageB((t + 3) & 3); }
        pA += BK; pB += BK;
        mfmaTile(FAa, FBa);
        if (t < NT - 3) {
            asm volatile("s_waitcnt vmcnt(4)" ::: "memory");   // tile t+2 resident
        } else {
            asm volatile("s_waitcnt vmcnt(0)" ::: "memory");
        }
        asm volatile("s_barrier" ::: "memory");

        // ===== half 2: compute tile t+1 (set b); read tile t+2 -> set a =====
        if (t + 2 < NT) readFrags(FAa, FBa, (t + 2) & 3);
        if (t + 4 < NT) { stageA((t + 4) & 3); stageB((t + 4) & 3); }
        pA += BK; pB += BK;
        mfmaTile(FAb, FBb);
        if (t + 1 < NT - 3) {
            asm volatile("s_waitcnt vmcnt(4)" ::: "memory");   // tile t+3 resident
        } else {
            asm volatile("s_waitcnt vmcnt(0)" ::: "memory");
        }
        asm volatile("s_barrier" ::: "memory");
    }

    // ---- epilogue: C/D layout col = lane&15, row = (lane>>4)*4 + reg
    const int rg = lane >> 4;
#pragma unroll
    for (int nf = 0; nf < 4; ++nf) {
        const int col = n0 + wc * 64 + nf * 16 + fr;
        const float bv = bias[col];
#pragma unroll
        for (int mf = 0; mf < 8; ++mf) {
            const int row = m0 + wr * 128 + mf * 16 + rg * 4;
            float* outp = C + (size_t)row * Ndim + col;
#pragma unroll
            for (int j = 0; j < 4; ++j) {
                float v = acc[mf][nf][j] + bv;
                v = fminf(fmaxf(v, -FMAXC), FMAXC);
                outp[(size_t)j * Ndim] = v;
            }
        }
    }
}

extern "C" void kernel_launch(void* const* d_in, const int* in_sizes, int n_in,
                              void* d_out, int out_size, void* d_ws, size_t ws_size,
                              hipStream_t stream) {
    const float* x    = (const float*)d_in[0];
    const int*   qw   = (const int*)d_in[1];
    const float* lut  = (const float*)d_in[2];
    const int*   rows = (const int*)d_in[3];
    const int*   cols = (const int*)d_in[4];
    const float* vals = (const float*)d_in[5];
    const float* bias = (const float*)d_in[6];
    float* out = (float*)d_out;

    ushort_t* x16 = (ushort_t*)d_ws;                       // 64 MiB
    ushort_t* w16 = x16 + (size_t)Mdim * Kdim;             // 32 MiB

    hipLaunchKernelGGL(dequant_kernel, dim3(Ndim), dim3(128), 0, stream,
                       qw, lut, rows, cols, vals, w16);
    hipLaunchKernelGGL(convx_kernel, dim3((Mdim * Kdim) / (256 * 8)), dim3(256), 0, stream,
                       x, x16);
    hipLaunchKernelGGL(gemm_kernel, dim3((Mdim / BM) * (Ndim / BN)), dim3(512), 0, stream,
                       x16, w16, bias, out);
}